// Round 5
// baseline (229.632 us; speedup 1.0000x reference)
//
#include <hip/hip_runtime.h>
#include <hip/hip_fp16.h>

#define Nn 50000
#define Ee 800000
#define D  128
#define SLOT 64

// role pattern: per 7 bids -> 1 scatter, 2 gemm, 4 norm
#define NGRP 782                   // scatter blocks; 782*1024 >= Ee
#define GRID_PRE (NGRP * 7)        // 5474 blocks
// gemm blocks: 2*782 = 1564 (32 rows each, covers 50048 >= Nn)
// norm blocks: 4*782 = 3128 (16 nodes each, covers 50048 >= Nn)

typedef _Float16 f16x8 __attribute__((ext_vector_type(8)));
typedef _Float16 h2    __attribute__((ext_vector_type(2)));
typedef float    f32x4 __attribute__((ext_vector_type(4)));

// node blob: 256 halfs per node = [sem16 row (128) | y16 row (128)] = 512 B

// ---------------- K0: zero cnt (replaces hipMemsetAsync graph node) ----------
// 49*256 int4 = 50,176 ints >= 50,048 (region padded to 51,200 ints)
__global__ __launch_bounds__(256) void k_zero(int* __restrict__ cnt) {
  int i = blockIdx.x * 256 + threadIdx.x;
  *(int4*)(cnt + i * 4) = (int4){0, 0, 0, 0};
}

// ---------------- K1 fused: roles interleaved mod 7, ZERO LDS ----------------
__global__ __launch_bounds__(256, 8) void k_pre(const float* __restrict__ x,
                                                const float* __restrict__ W,
                                                const float* __restrict__ b,
                                                const int* __restrict__ ei,
                                                const float* __restrict__ sem,
                                                __half* __restrict__ blob,
                                                int* __restrict__ cnt,
                                                unsigned short* __restrict__ slot16) {
  int bid = blockIdx.x, tid = threadIdx.x;
  int nb = bid / 7, r = bid % 7;

  if (r == 0) {
    // ---- slot scatter: 4 independent atomic->store chains per thread ----
    int base = nb * 1024 + tid;
#pragma unroll
    for (int u = 0; u < 4; u++) {
      int e = base + u * 256;
      if (e < Ee) {
        int s = ei[e], d = ei[Ee + e];
        int pos = atomicAdd(cnt + d, 1);
        if (pos < SLOT)                    // Poisson(16): P(deg>64) ~ 2e-18
          slot16[(size_t)d * SLOT + pos] = (unsigned short)s;
      }
    }
  } else if (r <= 2) {
    // ---- gemm role: 32 rows/block, wave col-split, W read direct from global ----
    int gb = nb * 2 + (r - 1);           // 0..1563
    int n0 = gb * 32;
    int wave = tid >> 6, lane = tid & 63;
    int rs = (wave >> 1) * 16;           // row strip 0/16
    int ch = (wave & 1) * 64;            // col half 0/64
    int g = lane >> 4, n16 = lane & 15;

    int arow = n0 + rs + n16; if (arow >= Nn) arow = Nn - 1;
    const float* xr = x + (size_t)arow * 128 + g * 8;
    union { f16x8 v; __half2 h[4]; } af[4];
#pragma unroll
    for (int kt = 0; kt < 4; kt++) {
      float4 u0 = *(const float4*)(xr + kt * 32);
      float4 u1 = *(const float4*)(xr + kt * 32 + 4);
      af[kt].h[0] = __floats2half2_rn(u0.x, u0.y);
      af[kt].h[1] = __floats2half2_rn(u0.z, u0.w);
      af[kt].h[2] = __floats2half2_rn(u1.x, u1.y);
      af[kt].h[3] = __floats2half2_rn(u1.z, u1.w);
    }

    f32x4 acc[4];
#pragma unroll
    for (int jt = 0; jt < 4; jt++) {
      float bias = b[ch + jt * 16 + n16];
      acc[jt] = (f32x4){bias, bias, bias, bias};
    }

    const float* wr = W + (size_t)(ch + n16) * 128 + g * 8;
#pragma unroll
    for (int kt = 0; kt < 4; kt++) {
#pragma unroll
      for (int jt = 0; jt < 4; jt++) {
        const float* wp = wr + (size_t)jt * 16 * 128 + kt * 32;
        float4 w0 = *(const float4*)(wp);
        float4 w1 = *(const float4*)(wp + 4);
        union { f16x8 v; __half2 h[4]; } bf;
        bf.h[0] = __floats2half2_rn(w0.x, w0.y);
        bf.h[1] = __floats2half2_rn(w0.z, w0.w);
        bf.h[2] = __floats2half2_rn(w1.x, w1.y);
        bf.h[3] = __floats2half2_rn(w1.z, w1.w);
        acc[jt] = __builtin_amdgcn_mfma_f32_16x16x32_f16(af[kt].v, bf.v, acc[jt], 0, 0, 0);
      }
    }
    // C/D: col = lane&15 (-> out col ch+jt*16+n16), row = g*4 + reg
#pragma unroll
    for (int jt = 0; jt < 4; jt++) {
#pragma unroll
      for (int rr = 0; rr < 4; rr++) {
        int row = n0 + rs + g * 4 + rr;
        if (row < Nn)
          blob[(size_t)row * 256 + 128 + ch + jt * 16 + n16] = __float2half(acc[jt][rr]);
      }
    }
  } else {
    // ---- sem normalize -> fp16 unit rows into blob sem-half, 16 nodes/block ----
    int idx = nb * 4 + (r - 3);          // 0..3127
    int nb16 = idx * 16;
    int wave = tid >> 6, lane = tid & 63;
#pragma unroll
    for (int it = 0; it < 4; it++) {
      int n = nb16 + it * 4 + wave;
      if (n < Nn) {
        const float2 v = *(const float2*)(sem + (size_t)n * D + 2 * lane);
        float p = v.x * v.x + v.y * v.y;
#pragma unroll
        for (int off = 32; off > 0; off >>= 1) p += __shfl_xor(p, off);
        float inv = 1.0f / fmaxf(sqrtf(p), 1e-8f);
        *(__half2*)(blob + (size_t)n * 256 + 2 * lane) = __floats2half2_rn(v.x * inv, v.y * inv);
      }
    }
  }
}

// ---------------- K2: fused per-dst, 16-lane groups, fdot2 dot products ------
__global__ __launch_bounds__(256) void k_fused(const __half* __restrict__ blob,
                                               const unsigned short* __restrict__ slot16,
                                               const int* __restrict__ cnt,
                                               float* __restrict__ out) {
  int d = (blockIdx.x * 256 + threadIdx.x) >> 6;
  int lane = threadIdx.x & 63;
  int g = lane >> 4, l16 = lane & 15;
  int c = cnt[d]; if (c > SLOT) c = SLOT;

  int sv = (lane < c) ? (int)slot16[(size_t)d * SLOT + lane] : 0;

  f16x8 dh = *(const f16x8*)(blob + (size_t)d * 256 + l16 * 8);

  float o[8] = {0, 0, 0, 0, 0, 0, 0, 0};
  float Sp = 0.0f;

  for (int i = 0; i < c; i += 4) {
    int e = i + g;
    int ce = e < c ? e : c - 1;
    int sa = __shfl(sv, ce);
    const __half* nbp = blob + (size_t)sa * 256;
    f16x8 rs = *(const f16x8*)(nbp + l16 * 8);         // sem row slice
    f16x8 ry = *(const f16x8*)(nbp + 128 + l16 * 8);   // y row slice
    float p = __builtin_amdgcn_fdot2((h2){rs[0], rs[1]}, (h2){dh[0], dh[1]}, 0.0f, false);
    p = __builtin_amdgcn_fdot2((h2){rs[2], rs[3]}, (h2){dh[2], dh[3]}, p, false);
    p = __builtin_amdgcn_fdot2((h2){rs[4], rs[5]}, (h2){dh[4], dh[5]}, p, false);
    p = __builtin_amdgcn_fdot2((h2){rs[6], rs[7]}, (h2){dh[6], dh[7]}, p, false);
    p += __shfl_xor(p, 1); p += __shfl_xor(p, 2);
    p += __shfl_xor(p, 4); p += __shfl_xor(p, 8);
    float ew = __expf(p); if (e >= c) ew = 0.0f;
    Sp += ew;
#pragma unroll
    for (int k = 0; k < 8; k++) o[k] += ew * (float)ry[k];
  }

#pragma unroll
  for (int k = 0; k < 8; k++) {
    o[k] += __shfl_xor(o[k], 16);
    o[k] += __shfl_xor(o[k], 32);
  }
  Sp += __shfl_xor(Sp, 16);
  Sp += __shfl_xor(Sp, 32);

  if (g == 0) {
    float inv = 1.0f / (Sp + 1e-16f);
    float4 r0; r0.x = o[0] * inv; r0.y = o[1] * inv; r0.z = o[2] * inv; r0.w = o[3] * inv;
    float4 r1; r1.x = o[4] * inv; r1.y = o[5] * inv; r1.z = o[6] * inv; r1.w = o[7] * inv;
    float* op = out + (size_t)d * D + l16 * 8;
    *(float4*)op = r0;
    *(float4*)(op + 4) = r1;
  }
}

// ---------------- launch ----------------
extern "C" void kernel_launch(void* const* d_in, const int* in_sizes, int n_in,
                              void* d_out, int out_size, void* d_ws, size_t ws_size,
                              hipStream_t stream) {
  const float* x     = (const float*)d_in[0];
  const int*   ei    = (const int*)d_in[1];    // int32 per harness contract
  const float* sem   = (const float*)d_in[2];
  const float* W_src = (const float*)d_in[3];
  const float* b_src = (const float*)d_in[4];
  float* out = (float*)d_out;

  char* ws = (char*)d_ws;
  const size_t O_BLOB = 0;          // N*256*2 = 25,600,000 (sem|y interleaved)
  const size_t O_CNT  = 25600000;   // 51,200-int padded region
  const size_t O_SS   = 25804800;   // N*64*2  =  6,400,000 (uint16 slots)
  const size_t NEED   = 32204800;
  if (ws_size < NEED) return;

  __half* blob = (__half*)(ws + O_BLOB);
  int* cnt = (int*)(ws + O_CNT);
  unsigned short* slot16 = (unsigned short*)(ws + O_SS);

  k_zero<<<49, 256, 0, stream>>>(cnt);
  k_pre<<<GRID_PRE, 256, 0, stream>>>(x, W_src, b_src, ei, sem, blob, cnt, slot16);
  k_fused<<<(Nn + 3) / 4, 256, 0, stream>>>(blob, slot16, cnt, out);
}

// Round 6
// 217.500 us; speedup vs baseline: 1.0558x; 1.0558x over previous
//
#include <hip/hip_runtime.h>
#include <hip/hip_fp16.h>

#define Nn 50000
#define Ee 800000
#define D  128
#define SLOT 64

typedef _Float16 f16x8 __attribute__((ext_vector_type(8)));
typedef _Float16 h2    __attribute__((ext_vector_type(2)));
typedef float    f32x4 __attribute__((ext_vector_type(4)));

// node blob: 256 halfs per node = [sem16 row (128) | y16 row (128)] = 512 B

// ---------------- K0: zero cnt ------------------------------------------------
__global__ __launch_bounds__(256) void k_zero(int* __restrict__ cnt) {
  int i = blockIdx.x * 256 + threadIdx.x;
  *(int4*)(cnt + i * 4) = (int4){0, 0, 0, 0};
}

// ---------------- K1: slot scatter (alone, attributable) ----------------------
// 782 blocks * 1024 edges; int4-vectorized index loads, 4 atomic chains/thread
__global__ __launch_bounds__(256) void k_scat(const int* __restrict__ ei,
                                              int* __restrict__ cnt,
                                              unsigned short* __restrict__ slot16) {
  int t = blockIdx.x * 256 + threadIdx.x;
  int e0 = t * 4;
  if (e0 >= Ee) return;
  int4 s4 = *(const int4*)(ei + e0);
  int4 d4 = *(const int4*)(ei + Ee + e0);
  int ss[4] = {s4.x, s4.y, s4.z, s4.w};
  int dd[4] = {d4.x, d4.y, d4.z, d4.w};
#pragma unroll
  for (int u = 0; u < 4; u++) {
    int e = e0 + u;
    if (e < Ee) {
      int pos = atomicAdd(cnt + dd[u], 1);
      if (pos < SLOT)                      // Poisson(16): P(deg>64) ~ 2e-18
        slot16[(size_t)dd[u] * SLOT + pos] = (unsigned short)ss[u];
    }
  }
}

// ---------------- K2: node kernel = gemm (W in LDS) + sem normalize -----------
// 32 nodes/block, 1563 blocks; LDS = 34,816 B -> 4 blocks/CU; VGPRs uncapped.
__global__ __launch_bounds__(256) void k_node(const float* __restrict__ x,
                                              const float* __restrict__ W,
                                              const float* __restrict__ b,
                                              const float* __restrict__ sem,
                                              __half* __restrict__ blob) {
  __shared__ __half sW16[128 * 136] __attribute__((aligned(16)));
  int bid = blockIdx.x, tid = threadIdx.x;
  int n0 = bid * 32;
  int wave = tid >> 6, lane = tid & 63;

  // stage W: 4096 float4, coalesced; fp32 -> fp16
  for (int r = 0; r < 16; r++) {
    int i = tid + 256 * r;
    int row = i >> 5, c4 = (i & 31) << 2;
    float4 w = *(const float4*)(W + (size_t)row * 128 + c4);
    __half2* dst = (__half2*)&sW16[row * 136 + c4];
    dst[0] = __floats2half2_rn(w.x, w.y);
    dst[1] = __floats2half2_rn(w.z, w.w);
  }

  // norm role: each wave normalizes 8 nodes (lane-pair = 2 dims, shfl reduce)
#pragma unroll
  for (int it = 0; it < 8; it++) {
    int n = n0 + it * 4 + wave;
    if (n < Nn) {
      const float2 v = *(const float2*)(sem + (size_t)n * D + 2 * lane);
      float p = v.x * v.x + v.y * v.y;
#pragma unroll
      for (int off = 32; off > 0; off >>= 1) p += __shfl_xor(p, off);
      float inv = 1.0f / fmaxf(sqrtf(p), 1e-8f);
      *(__half2*)(blob + (size_t)n * 256 + 2 * lane) = __floats2half2_rn(v.x * inv, v.y * inv);
    }
  }

  // gemm role: 32 rows, waves col-split: rs = row strip, ch = col half
  int rs = (wave >> 1) * 16;           // 0 / 16
  int ch = (wave & 1) * 64;            // 0 / 64
  int g = lane >> 4, n16 = lane & 15;

  int arow = n0 + rs + n16; if (arow >= Nn) arow = Nn - 1;
  const float* xr = x + (size_t)arow * 128 + g * 8;
  union { f16x8 v; __half2 h[4]; } af[4];
#pragma unroll
  for (int kt = 0; kt < 4; kt++) {
    float4 u0 = *(const float4*)(xr + kt * 32);
    float4 u1 = *(const float4*)(xr + kt * 32 + 4);
    af[kt].h[0] = __floats2half2_rn(u0.x, u0.y);
    af[kt].h[1] = __floats2half2_rn(u0.z, u0.w);
    af[kt].h[2] = __floats2half2_rn(u1.x, u1.y);
    af[kt].h[3] = __floats2half2_rn(u1.z, u1.w);
  }

  __syncthreads();

  f32x4 acc[4];
#pragma unroll
  for (int jt = 0; jt < 4; jt++) {
    float bias = b[ch + jt * 16 + n16];
    acc[jt] = (f32x4){bias, bias, bias, bias};
  }
#pragma unroll
  for (int kt = 0; kt < 4; kt++) {
#pragma unroll
    for (int jt = 0; jt < 4; jt++) {
      f16x8 bf = *(const f16x8*)(&sW16[(ch + jt * 16 + n16) * 136 + kt * 32 + g * 8]);
      acc[jt] = __builtin_amdgcn_mfma_f32_16x16x32_f16(af[kt].v, bf, acc[jt], 0, 0, 0);
    }
  }
  // C/D: col = lane&15 (-> out col ch+jt*16+n16), row = g*4 + reg
#pragma unroll
  for (int jt = 0; jt < 4; jt++) {
#pragma unroll
    for (int rr = 0; rr < 4; rr++) {
      int row = n0 + rs + g * 4 + rr;
      if (row < Nn)
        blob[(size_t)row * 256 + 128 + ch + jt * 16 + n16] = __float2half(acc[jt][rr]);
    }
  }
}

// ---------------- K3: fused per-dst, 16-lane groups, fdot2 dot products ------
__global__ __launch_bounds__(256) void k_fused(const __half* __restrict__ blob,
                                               const unsigned short* __restrict__ slot16,
                                               const int* __restrict__ cnt,
                                               float* __restrict__ out) {
  int d = (blockIdx.x * 256 + threadIdx.x) >> 6;
  int lane = threadIdx.x & 63;
  int g = lane >> 4, l16 = lane & 15;
  int c = cnt[d]; if (c > SLOT) c = SLOT;

  int sv = (lane < c) ? (int)slot16[(size_t)d * SLOT + lane] : 0;

  f16x8 dh = *(const f16x8*)(blob + (size_t)d * 256 + l16 * 8);

  float o[8] = {0, 0, 0, 0, 0, 0, 0, 0};
  float Sp = 0.0f;

  for (int i = 0; i < c; i += 4) {
    int e = i + g;
    int ce = e < c ? e : c - 1;
    int sa = __shfl(sv, ce);
    const __half* nbp = blob + (size_t)sa * 256;
    f16x8 rs = *(const f16x8*)(nbp + l16 * 8);         // sem row slice
    f16x8 ry = *(const f16x8*)(nbp + 128 + l16 * 8);   // y row slice
    float p = __builtin_amdgcn_fdot2((h2){rs[0], rs[1]}, (h2){dh[0], dh[1]}, 0.0f, false);
    p = __builtin_amdgcn_fdot2((h2){rs[2], rs[3]}, (h2){dh[2], dh[3]}, p, false);
    p = __builtin_amdgcn_fdot2((h2){rs[4], rs[5]}, (h2){dh[4], dh[5]}, p, false);
    p = __builtin_amdgcn_fdot2((h2){rs[6], rs[7]}, (h2){dh[6], dh[7]}, p, false);
    p += __shfl_xor(p, 1); p += __shfl_xor(p, 2);
    p += __shfl_xor(p, 4); p += __shfl_xor(p, 8);
    float ew = __expf(p); if (e >= c) ew = 0.0f;
    Sp += ew;
#pragma unroll
    for (int k = 0; k < 8; k++) o[k] += ew * (float)ry[k];
  }

#pragma unroll
  for (int k = 0; k < 8; k++) {
    o[k] += __shfl_xor(o[k], 16);
    o[k] += __shfl_xor(o[k], 32);
  }
  Sp += __shfl_xor(Sp, 16);
  Sp += __shfl_xor(Sp, 32);

  if (g == 0) {
    float inv = 1.0f / (Sp + 1e-16f);
    float4 r0; r0.x = o[0] * inv; r0.y = o[1] * inv; r0.z = o[2] * inv; r0.w = o[3] * inv;
    float4 r1; r1.x = o[4] * inv; r1.y = o[5] * inv; r1.z = o[6] * inv; r1.w = o[7] * inv;
    float* op = out + (size_t)d * D + l16 * 8;
    *(float4*)op = r0;
    *(float4*)(op + 4) = r1;
  }
}

// ---------------- launch ----------------
extern "C" void kernel_launch(void* const* d_in, const int* in_sizes, int n_in,
                              void* d_out, int out_size, void* d_ws, size_t ws_size,
                              hipStream_t stream) {
  const float* x     = (const float*)d_in[0];
  const int*   ei    = (const int*)d_in[1];    // int32 per harness contract
  const float* sem   = (const float*)d_in[2];
  const float* W_src = (const float*)d_in[3];
  const float* b_src = (const float*)d_in[4];
  float* out = (float*)d_out;

  char* ws = (char*)d_ws;
  const size_t O_BLOB = 0;          // N*256*2 = 25,600,000 (sem|y interleaved)
  const size_t O_CNT  = 25600000;   // 51,200-int padded region
  const size_t O_SS   = 25804800;   // N*64*2  =  6,400,000 (uint16 slots)
  const size_t NEED   = 32204800;
  if (ws_size < NEED) return;

  __half* blob = (__half*)(ws + O_BLOB);
  int* cnt = (int*)(ws + O_CNT);
  unsigned short* slot16 = (unsigned short*)(ws + O_SS);

  k_zero<<<49, 256, 0, stream>>>(cnt);
  k_scat<<<782, 256, 0, stream>>>(ei, cnt, slot16);
  k_node<<<1563, 256, 0, stream>>>(x, W_src, b_src, sem, blob);
  k_fused<<<(Nn + 3) / 4, 256, 0, stream>>>(blob, slot16, cnt, out);
}